// Round 1
// baseline (855.761 us; speedup 1.0000x reference)
//
#include <hip/hip_runtime.h>

#define EPSF 1e-5f

typedef _Float16 f16x8 __attribute__((ext_vector_type(8)));
typedef float f32x4 __attribute__((ext_vector_type(4)));

__device__ __forceinline__ void gload_lds16(const _Float16* g, _Float16* l) {
  __builtin_amdgcn_global_load_lds(
      (const __attribute__((address_space(1))) unsigned int*)g,
      (__attribute__((address_space(3))) unsigned int*)l, 16, 0, 0);
}

__device__ __forceinline__ f16x8 cvt8(float4 a, float4 b) {
  f16x8 h;
  h[0] = (_Float16)a.x; h[1] = (_Float16)a.y; h[2] = (_Float16)a.z; h[3] = (_Float16)a.w;
  h[4] = (_Float16)b.x; h[5] = (_Float16)b.y; h[6] = (_Float16)b.z; h[7] = (_Float16)b.w;
  return h;
}

// ================= kernel 0: opinion weights =================
__global__ void prep_opin_k(const float* __restrict__ gold, const float* __restrict__ pred,
                            const float* __restrict__ gprob, float* __restrict__ opin, int n) {
  int i = blockIdx.x * 256 + threadIdx.x;
  if (i >= n) return;
  float gp = gprob[0];
  float go = gold[i * 5 + 1] + gold[i * 5 + 2];
  float po = pred[i * 5 + 3] + pred[i * 5 + 4];
  opin[i] = gp * go + (1.0f - gp) * po;
}

// ================= kernel 1: XT = fp16(x @ W^T + b) =================
// M=32768 (b,s), N=1024 (e), K=1024 (d). NT: both operands K-contiguous.
__global__ __launch_bounds__(256) void gemm1_k(const float* __restrict__ X,
                                               const float* __restrict__ Wt,
                                               const float* __restrict__ bias,
                                               _Float16* __restrict__ XT) {
  __shared__ _Float16 As[128 * 32];
  __shared__ _Float16 Bs[128 * 32];
  const int tid = threadIdx.x;
  const int wave = tid >> 6, lane = tid & 63;
  const int wm = wave >> 1, wn = wave & 1;
  const int quad = lane >> 4, nl = lane & 15;
  const long m0 = (long)blockIdx.y * 128;
  const int n0 = blockIdx.x * 128;

  f32x4 acc[4][4];
  f32x4 zero = {0.f, 0.f, 0.f, 0.f};
#pragma unroll
  for (int i = 0; i < 4; ++i)
#pragma unroll
    for (int j = 0; j < 4; ++j) acc[i][j] = zero;

  const int crow = tid >> 2;       // 0..63
  const int ckc = (tid & 3) * 8;   // 0,8,16,24

  for (int k0 = 0; k0 < 1024; k0 += 32) {
#pragma unroll
    for (int it = 0; it < 2; ++it) {
      int row = it * 64 + crow;
      const float* sa = X + (m0 + row) * 1024 + k0 + ckc;
      float4 a0 = *(const float4*)sa;
      float4 a1 = *(const float4*)(sa + 4);
      *(f16x8*)&As[row * 32 + ckc] = cvt8(a0, a1);
      const float* sb = Wt + (long)(n0 + row) * 1024 + k0 + ckc;
      float4 b0 = *(const float4*)sb;
      float4 b1 = *(const float4*)(sb + 4);
      *(f16x8*)&Bs[row * 32 + ckc] = cvt8(b0, b1);
    }
    __syncthreads();
    f16x8 af[4], bf[4];
#pragma unroll
    for (int mi = 0; mi < 4; ++mi)
      af[mi] = *(const f16x8*)&As[(wm * 64 + mi * 16 + nl) * 32 + quad * 8];
#pragma unroll
    for (int ni = 0; ni < 4; ++ni)
      bf[ni] = *(const f16x8*)&Bs[(wn * 64 + ni * 16 + nl) * 32 + quad * 8];
#pragma unroll
    for (int mi = 0; mi < 4; ++mi)
#pragma unroll
      for (int ni = 0; ni < 4; ++ni)
        acc[mi][ni] = __builtin_amdgcn_mfma_f32_16x16x32_f16(af[mi], bf[ni], acc[mi][ni], 0, 0, 0);
    __syncthreads();
  }

#pragma unroll
  for (int mi = 0; mi < 4; ++mi) {
    long gm = m0 + wm * 64 + mi * 16 + quad * 4;
#pragma unroll
    for (int ni = 0; ni < 4; ++ni) {
      int gn = n0 + wn * 64 + ni * 16 + nl;
      float bv = bias[gn];
#pragma unroll
      for (int r = 0; r < 4; ++r)
        XT[(gm + r) * 1024 + gn] = (_Float16)(acc[mi][ni][r] + bv);
    }
  }
}

// ================= kernel 2: P = fp16(exp(tanh(XT @ x^T * decay * opin))), denom += rowsum =================
__global__ __launch_bounds__(256) void scores_k(const _Float16* __restrict__ XT,
                                                const float* __restrict__ X,
                                                const float* __restrict__ opin,
                                                _Float16* __restrict__ P,
                                                float* __restrict__ denom) {
  __shared__ _Float16 As[128 * 32];
  __shared__ _Float16 Bs[128 * 32];
  const int tid = threadIdx.x;
  const int wave = tid >> 6, lane = tid & 63;
  const int wm = wave >> 1, wn = wave & 1;
  const int quad = lane >> 4, nl = lane & 15;
  const int b = blockIdx.z;
  const int s0 = blockIdx.y * 128;
  const int t0 = blockIdx.x * 128;
  const long base = (long)b * 1024;

  f32x4 acc[4][4];
  f32x4 zero = {0.f, 0.f, 0.f, 0.f};
#pragma unroll
  for (int i = 0; i < 4; ++i)
#pragma unroll
    for (int j = 0; j < 4; ++j) acc[i][j] = zero;

  const int crow = tid >> 2;
  const int ckc = (tid & 3) * 8;

  for (int k0 = 0; k0 < 1024; k0 += 32) {
#pragma unroll
    for (int it = 0; it < 2; ++it) {
      // A: fp16 direct-to-LDS. chunk c = it*256 + tid; lane-contiguous per wave.
      int c = it * 256 + tid;
      const _Float16* sa = XT + (base + s0 + (c >> 2)) * 1024 + k0 + (c & 3) * 8;
      gload_lds16(sa, &As[(it * 256 + wave * 64) * 8]);
      // B: x fp32 -> cvt -> LDS
      int row = it * 64 + crow;
      const float* sb = X + (base + t0 + row) * 1024 + k0 + ckc;
      float4 b0 = *(const float4*)sb;
      float4 b1 = *(const float4*)(sb + 4);
      *(f16x8*)&Bs[row * 32 + ckc] = cvt8(b0, b1);
    }
    __syncthreads();
    f16x8 af[4], bf[4];
#pragma unroll
    for (int mi = 0; mi < 4; ++mi)
      af[mi] = *(const f16x8*)&As[(wm * 64 + mi * 16 + nl) * 32 + quad * 8];
#pragma unroll
    for (int ni = 0; ni < 4; ++ni)
      bf[ni] = *(const f16x8*)&Bs[(wn * 64 + ni * 16 + nl) * 32 + quad * 8];
#pragma unroll
    for (int mi = 0; mi < 4; ++mi)
#pragma unroll
      for (int ni = 0; ni < 4; ++ni)
        acc[mi][ni] = __builtin_amdgcn_mfma_f32_16x16x32_f16(af[mi], bf[ni], acc[mi][ni], 0, 0, 0);
    __syncthreads();
  }

  // epilogue: decay * opin -> exp(tanh) -> mask diag -> store fp16 + row-sum atomics
#pragma unroll
  for (int mi = 0; mi < 4; ++mi) {
#pragma unroll
    for (int r = 0; r < 4; ++r) {
      int s = s0 + wm * 64 + mi * 16 + quad * 4 + r;
      float opv = opin[b * 1024 + s];
      float rs = 0.f;
#pragma unroll
      for (int ni = 0; ni < 4; ++ni) {
        int t = t0 + wn * 64 + ni * 16 + nl;
        float loc = fabsf((float)(s - t));
        float arg = acc[mi][ni][r] * (1.0f / (loc + EPSF)) * opv;
        float th = 1.f - 2.f / (__expf(2.f * arg) + 1.f);  // tanh(arg)
        float p = __expf(th);
        if (s == t) p = 0.f;
        P[(base + s) * 1024 + t] = (_Float16)p;
        rs += p;
      }
      // reduce over the 16 lanes that share this row (nl = 0..15)
      rs += __shfl_xor(rs, 1);
      rs += __shfl_xor(rs, 2);
      rs += __shfl_xor(rs, 4);
      rs += __shfl_xor(rs, 8);
      if (nl == 0) atomicAdd(&denom[b * 1024 + s], rs);
    }
  }
}

// ================= kernel 3: out = (P @ x) / (denom + eps) =================
// M=1024 (s), N=1024 (d), K=1024 (t). B operand transposed into LDS.
__global__ __launch_bounds__(256) void pv_k(const _Float16* __restrict__ P,
                                            const float* __restrict__ X,
                                            const float* __restrict__ denom,
                                            float* __restrict__ out) {
  __shared__ _Float16 As[128 * 32];
  __shared__ _Float16 BsT[128 * 40];  // [d 128][t 32], row stride 40 halves (80B, 16B-aligned)
  const int tid = threadIdx.x;
  const int wave = tid >> 6, lane = tid & 63;
  const int wm = wave >> 1, wn = wave & 1;
  const int quad = lane >> 4, nl = lane & 15;
  const int b = blockIdx.z;
  const int s0 = blockIdx.y * 128;
  const int d0 = blockIdx.x * 128;
  const long base = (long)b * 1024;

  f32x4 acc[4][4];
  f32x4 zero = {0.f, 0.f, 0.f, 0.f};
#pragma unroll
  for (int i = 0; i < 4; ++i)
#pragma unroll
    for (int j = 0; j < 4; ++j) acc[i][j] = zero;

  for (int k0 = 0; k0 < 1024; k0 += 32) {
#pragma unroll
    for (int it = 0; it < 2; ++it) {
      int c = it * 256 + tid;
      const _Float16* sa = P + (base + s0 + (c >> 2)) * 1024 + k0 + (c & 3) * 8;
      gload_lds16(sa, &As[(it * 256 + wave * 64) * 8]);
    }
#pragma unroll
    for (int it = 0; it < 4; ++it) {
      int t = it * 8 + (tid >> 5);
      int d4 = (tid & 31) * 4;
      const float* sb = X + (base + k0 + t) * 1024 + d0 + d4;
      float4 v = *(const float4*)sb;
      BsT[(d4 + 0) * 40 + t] = (_Float16)v.x;
      BsT[(d4 + 1) * 40 + t] = (_Float16)v.y;
      BsT[(d4 + 2) * 40 + t] = (_Float16)v.z;
      BsT[(d4 + 3) * 40 + t] = (_Float16)v.w;
    }
    __syncthreads();
    f16x8 af[4], bf[4];
#pragma unroll
    for (int mi = 0; mi < 4; ++mi)
      af[mi] = *(const f16x8*)&As[(wm * 64 + mi * 16 + nl) * 32 + quad * 8];
#pragma unroll
    for (int ni = 0; ni < 4; ++ni)
      bf[ni] = *(const f16x8*)&BsT[(wn * 64 + ni * 16 + nl) * 40 + quad * 8];
#pragma unroll
    for (int mi = 0; mi < 4; ++mi)
#pragma unroll
      for (int ni = 0; ni < 4; ++ni)
        acc[mi][ni] = __builtin_amdgcn_mfma_f32_16x16x32_f16(af[mi], bf[ni], acc[mi][ni], 0, 0, 0);
    __syncthreads();
  }

#pragma unroll
  for (int mi = 0; mi < 4; ++mi) {
#pragma unroll
    for (int r = 0; r < 4; ++r) {
      int s = s0 + wm * 64 + mi * 16 + quad * 4 + r;
      float inv = 1.0f / (denom[b * 1024 + s] + EPSF);
#pragma unroll
      for (int ni = 0; ni < 4; ++ni) {
        int d = d0 + wn * 64 + ni * 16 + nl;
        out[(base + s) * 1024 + d] = acc[mi][ni][r] * inv;
      }
    }
  }
}

extern "C" void kernel_launch(void* const* d_in, const int* in_sizes, int n_in,
                              void* d_out, int out_size, void* d_ws, size_t ws_size,
                              hipStream_t stream) {
  (void)in_sizes; (void)n_in; (void)out_size; (void)ws_size;
  const int B = 32, S = 1024;
  const int BS = B * S;

  const float* x     = (const float*)d_in[0];
  const float* W     = (const float*)d_in[1];
  const float* bias  = (const float*)d_in[2];
  const float* gold  = (const float*)d_in[3];
  const float* pred  = (const float*)d_in[4];
  const float* gprob = (const float*)d_in[5];

  // workspace: P (64MB fp16) | opin (128KB) | denom (128KB)   -> ~64.5 MB
  char* ws = (char*)d_ws;
  _Float16* P  = (_Float16*)ws;
  float* opin  = (float*)(ws + (size_t)BS * 1024 * sizeof(_Float16));
  float* denom = opin + BS;

  // x_tran (fp16, 64MB) lives in the front half of d_out; it is fully consumed
  // by scores_k before pv_k overwrites d_out with the final fp32 output.
  _Float16* XT = (_Float16*)d_out;
  float* out   = (float*)d_out;

  hipMemsetAsync(denom, 0, BS * sizeof(float), stream);
  prep_opin_k<<<BS / 256, 256, 0, stream>>>(gold, pred, gprob, opin, BS);
  gemm1_k<<<dim3(8, 256), 256, 0, stream>>>(x, W, bias, XT);
  scores_k<<<dim3(8, 8, 32), 256, 0, stream>>>(XT, x, opin, P, denom);
  pv_k<<<dim3(8, 8, 32), 256, 0, stream>>>(P, x, denom, out);
}

// Round 2
// 709.456 us; speedup vs baseline: 1.2062x; 1.2062x over previous
//
#include <hip/hip_runtime.h>

#define EPSF 1e-5f

typedef _Float16 f16x8 __attribute__((ext_vector_type(8)));
typedef float f32x4 __attribute__((ext_vector_type(4)));

__device__ __forceinline__ void gload_lds16(const _Float16* g, _Float16* l) {
  __builtin_amdgcn_global_load_lds(
      (const __attribute__((address_space(1))) unsigned int*)g,
      (__attribute__((address_space(3))) unsigned int*)l, 16, 0, 0);
}

__device__ __forceinline__ f16x8 cvt8(float4 a, float4 b) {
  f16x8 h;
  h[0] = (_Float16)a.x; h[1] = (_Float16)a.y; h[2] = (_Float16)a.z; h[3] = (_Float16)a.w;
  h[4] = (_Float16)b.x; h[5] = (_Float16)b.y; h[6] = (_Float16)b.z; h[7] = (_Float16)b.w;
  return h;
}

// ================= kernel 0a: opinion weights =================
__global__ void prep_opin_k(const float* __restrict__ gold, const float* __restrict__ pred,
                            const float* __restrict__ gprob, float* __restrict__ opin, int n) {
  int i = blockIdx.x * 256 + threadIdx.x;
  if (i >= n) return;
  float gp = gprob[0];
  float go = gold[i * 5 + 1] + gold[i * 5 + 2];
  float po = pred[i * 5 + 3] + pred[i * 5 + 4];
  opin[i] = gp * go + (1.0f - gp) * po;
}

// ================= kernel 0b: Xh = fp16(x) =================
__global__ __launch_bounds__(256) void prep_xh_k(const float* __restrict__ x,
                                                 _Float16* __restrict__ Xh) {
  long i = ((long)blockIdx.x * 256 + threadIdx.x) * 8;
  float4 a = *(const float4*)(x + i);
  float4 b = *(const float4*)(x + i + 4);
  *(f16x8*)(Xh + i) = cvt8(a, b);
}

// ================= kernel 1: XT = fp16(Xh @ W^T + b) =================
// M=32768 (b,s), N=1024 (e), K=1024 (d). A via global_load_lds (fp16), B fp32+cvt.
__global__ __launch_bounds__(256) void gemm1_k(const _Float16* __restrict__ Xh,
                                               const float* __restrict__ Wt,
                                               const float* __restrict__ bias,
                                               _Float16* __restrict__ XT) {
  __shared__ _Float16 As[128 * 32];
  __shared__ _Float16 Bs[128 * 32];
  const int tid = threadIdx.x;
  const int wave = tid >> 6, lane = tid & 63;
  const int wm = wave >> 1, wn = wave & 1;
  const int quad = lane >> 4, nl = lane & 15;
  const long m0 = (long)blockIdx.y * 128;
  const int n0 = blockIdx.x * 128;

  f32x4 acc[4][4];
  f32x4 zero = {0.f, 0.f, 0.f, 0.f};
#pragma unroll
  for (int i = 0; i < 4; ++i)
#pragma unroll
    for (int j = 0; j < 4; ++j) acc[i][j] = zero;

  const int crow = tid >> 2;       // 0..63
  const int ckc = (tid & 3) * 8;   // 0,8,16,24

  for (int k0 = 0; k0 < 1024; k0 += 32) {
#pragma unroll
    for (int it = 0; it < 2; ++it) {
      int c = it * 256 + tid;
      gload_lds16(Xh + (m0 + (c >> 2)) * 1024 + k0 + (c & 3) * 8,
                  &As[(it * 256 + wave * 64) * 8]);
      int row = it * 64 + crow;
      const float* sb = Wt + (long)(n0 + row) * 1024 + k0 + ckc;
      float4 b0 = *(const float4*)sb;
      float4 b1 = *(const float4*)(sb + 4);
      *(f16x8*)&Bs[row * 32 + ckc] = cvt8(b0, b1);
    }
    __syncthreads();
    f16x8 af[4], bf[4];
#pragma unroll
    for (int mi = 0; mi < 4; ++mi)
      af[mi] = *(const f16x8*)&As[(wm * 64 + mi * 16 + nl) * 32 + quad * 8];
#pragma unroll
    for (int ni = 0; ni < 4; ++ni)
      bf[ni] = *(const f16x8*)&Bs[(wn * 64 + ni * 16 + nl) * 32 + quad * 8];
#pragma unroll
    for (int mi = 0; mi < 4; ++mi)
#pragma unroll
      for (int ni = 0; ni < 4; ++ni)
        acc[mi][ni] = __builtin_amdgcn_mfma_f32_16x16x32_f16(af[mi], bf[ni], acc[mi][ni], 0, 0, 0);
    __syncthreads();
  }

#pragma unroll
  for (int mi = 0; mi < 4; ++mi) {
    long gm = m0 + wm * 64 + mi * 16 + quad * 4;
#pragma unroll
    for (int ni = 0; ni < 4; ++ni) {
      int gn = n0 + wn * 64 + ni * 16 + nl;
      float bv = bias[gn];
#pragma unroll
      for (int r = 0; r < 4; ++r)
        XT[(gm + r) * 1024 + gn] = (_Float16)(acc[mi][ni][r] + bv);
    }
  }
}

// ================= kernel 2: P = fp16(exp(tanh(XT @ Xh^T * decay * opin))), denom += rowsum ===
__global__ __launch_bounds__(256) void scores_k(const _Float16* __restrict__ XT,
                                                const _Float16* __restrict__ Xh,
                                                const float* __restrict__ opin,
                                                _Float16* __restrict__ P,
                                                float* __restrict__ denom) {
  __shared__ _Float16 As[128 * 32];
  __shared__ _Float16 Bs[128 * 32];
  const int tid = threadIdx.x;
  const int wave = tid >> 6, lane = tid & 63;
  const int wm = wave >> 1, wn = wave & 1;
  const int quad = lane >> 4, nl = lane & 15;
  const int b = blockIdx.z;
  const int s0 = blockIdx.y * 128;
  const int t0 = blockIdx.x * 128;
  const long base = (long)b * 1024;

  f32x4 acc[4][4];
  f32x4 zero = {0.f, 0.f, 0.f, 0.f};
#pragma unroll
  for (int i = 0; i < 4; ++i)
#pragma unroll
    for (int j = 0; j < 4; ++j) acc[i][j] = zero;

  for (int k0 = 0; k0 < 1024; k0 += 32) {
#pragma unroll
    for (int it = 0; it < 2; ++it) {
      int c = it * 256 + tid;
      gload_lds16(XT + (base + s0 + (c >> 2)) * 1024 + k0 + (c & 3) * 8,
                  &As[(it * 256 + wave * 64) * 8]);
      gload_lds16(Xh + (base + t0 + (c >> 2)) * 1024 + k0 + (c & 3) * 8,
                  &Bs[(it * 256 + wave * 64) * 8]);
    }
    __syncthreads();
    f16x8 af[4], bf[4];
#pragma unroll
    for (int mi = 0; mi < 4; ++mi)
      af[mi] = *(const f16x8*)&As[(wm * 64 + mi * 16 + nl) * 32 + quad * 8];
#pragma unroll
    for (int ni = 0; ni < 4; ++ni)
      bf[ni] = *(const f16x8*)&Bs[(wn * 64 + ni * 16 + nl) * 32 + quad * 8];
#pragma unroll
    for (int mi = 0; mi < 4; ++mi)
#pragma unroll
      for (int ni = 0; ni < 4; ++ni)
        acc[mi][ni] = __builtin_amdgcn_mfma_f32_16x16x32_f16(af[mi], bf[ni], acc[mi][ni], 0, 0, 0);
    __syncthreads();
  }

  // epilogue: decay * opin -> exp(tanh) -> mask diag -> store fp16 + row-sum atomics
#pragma unroll
  for (int mi = 0; mi < 4; ++mi) {
#pragma unroll
    for (int r = 0; r < 4; ++r) {
      int s = s0 + wm * 64 + mi * 16 + quad * 4 + r;
      float opv = opin[b * 1024 + s];
      float rs = 0.f;
#pragma unroll
      for (int ni = 0; ni < 4; ++ni) {
        int t = t0 + wn * 64 + ni * 16 + nl;
        float loc = fabsf((float)(s - t));
        float arg = acc[mi][ni][r] * (1.0f / (loc + EPSF)) * opv;
        float th = 1.f - 2.f / (__expf(2.f * arg) + 1.f);  // tanh(arg)
        float p = __expf(th);
        if (s == t) p = 0.f;
        P[(base + s) * 1024 + t] = (_Float16)p;
        rs += p;
      }
      rs += __shfl_xor(rs, 1);
      rs += __shfl_xor(rs, 2);
      rs += __shfl_xor(rs, 4);
      rs += __shfl_xor(rs, 8);
      if (nl == 0) atomicAdd(&denom[b * 1024 + s], rs);
    }
  }
}

// ================= kernel 3: out = (P @ x) / (denom + eps) =================
// M=1024 (s), N=1024 (d), K=1024 (t). B: gather-transpose x fp32 -> fp16 LDS, conflict-free.
__global__ __launch_bounds__(256) void pv_k(const _Float16* __restrict__ P,
                                            const float* __restrict__ X,
                                            const float* __restrict__ denom,
                                            float* __restrict__ out) {
  __shared__ _Float16 As[128 * 32];
  __shared__ _Float16 BsT[128 * 40];  // [d 128][t 32+pad], row stride 80B (16B-aligned)
  const int tid = threadIdx.x;
  const int wave = tid >> 6, lane = tid & 63;
  const int wm = wave >> 1, wn = wave & 1;
  const int quad = lane >> 4, nl = lane & 15;
  const int b = blockIdx.z;
  const int s0 = blockIdx.y * 128;
  const int d0 = blockIdx.x * 128;
  const long base = (long)b * 1024;

  const int dcol = tid & 127;   // this thread's d-row in BsT
  const int tg = tid >> 7;      // t half-tile: 0 -> t 0..15, 1 -> t 16..31

  f32x4 acc[4][4];
  f32x4 zero = {0.f, 0.f, 0.f, 0.f};
#pragma unroll
  for (int i = 0; i < 4; ++i)
#pragma unroll
    for (int j = 0; j < 4; ++j) acc[i][j] = zero;

  for (int k0 = 0; k0 < 1024; k0 += 32) {
#pragma unroll
    for (int it = 0; it < 2; ++it) {
      int c = it * 256 + tid;
      gload_lds16(P + (base + s0 + (c >> 2)) * 1024 + k0 + (c & 3) * 8,
                  &As[(it * 256 + wave * 64) * 8]);
    }
    // gather 16 t-values for one d column (each load coalesced across lanes),
    // write two b128s of contiguous t -> zero-conflict transpose
    {
      const float* xb = X + (base + k0 + tg * 16) * 1024 + d0 + dcol;
      float v[16];
#pragma unroll
      for (int j = 0; j < 16; ++j) v[j] = xb[j * 1024];
      f16x8 h0, h1;
#pragma unroll
      for (int j = 0; j < 8; ++j) { h0[j] = (_Float16)v[j]; h1[j] = (_Float16)v[8 + j]; }
      *(f16x8*)&BsT[dcol * 40 + tg * 16] = h0;
      *(f16x8*)&BsT[dcol * 40 + tg * 16 + 8] = h1;
    }
    __syncthreads();
    f16x8 af[4], bf[4];
#pragma unroll
    for (int mi = 0; mi < 4; ++mi)
      af[mi] = *(const f16x8*)&As[(wm * 64 + mi * 16 + nl) * 32 + quad * 8];
#pragma unroll
    for (int ni = 0; ni < 4; ++ni)
      bf[ni] = *(const f16x8*)&BsT[(wn * 64 + ni * 16 + nl) * 40 + quad * 8];
#pragma unroll
    for (int mi = 0; mi < 4; ++mi)
#pragma unroll
      for (int ni = 0; ni < 4; ++ni)
        acc[mi][ni] = __builtin_amdgcn_mfma_f32_16x16x32_f16(af[mi], bf[ni], acc[mi][ni], 0, 0, 0);
    __syncthreads();
  }

#pragma unroll
  for (int mi = 0; mi < 4; ++mi) {
#pragma unroll
    for (int r = 0; r < 4; ++r) {
      int s = s0 + wm * 64 + mi * 16 + quad * 4 + r;
      float inv = 1.0f / (denom[b * 1024 + s] + EPSF);
#pragma unroll
      for (int ni = 0; ni < 4; ++ni) {
        int d = d0 + wn * 64 + ni * 16 + nl;
        out[(base + s) * 1024 + d] = acc[mi][ni][r] * inv;
      }
    }
  }
}

extern "C" void kernel_launch(void* const* d_in, const int* in_sizes, int n_in,
                              void* d_out, int out_size, void* d_ws, size_t ws_size,
                              hipStream_t stream) {
  (void)in_sizes; (void)n_in; (void)out_size; (void)ws_size;
  const int B = 32, S = 1024;
  const int BS = B * S;

  const float* x     = (const float*)d_in[0];
  const float* W     = (const float*)d_in[1];
  const float* bias  = (const float*)d_in[2];
  const float* gold  = (const float*)d_in[3];
  const float* pred  = (const float*)d_in[4];
  const float* gprob = (const float*)d_in[5];

  // workspace: P (64MB fp16) | opin (128KB) | denom (128KB)   -> ~64.25 MB
  char* ws = (char*)d_ws;
  _Float16* P  = (_Float16*)ws;
  float* opin  = (float*)(ws + (size_t)BS * 1024 * sizeof(_Float16));
  float* denom = opin + BS;

  // d_out (128MB fp32) double-duty:
  //   front 64MB = XT (fp16 x_tran): written by gemm1, consumed by scores
  //   back  64MB = Xh (fp16 x):      written by prep_xh, consumed by gemm1+scores
  // Both are dead before pv_k overwrites d_out with the final fp32 output.
  _Float16* XT = (_Float16*)d_out;
  _Float16* Xh = XT + (size_t)BS * 1024;
  float* out   = (float*)d_out;

  hipMemsetAsync(denom, 0, BS * sizeof(float), stream);
  prep_opin_k<<<BS / 256, 256, 0, stream>>>(gold, pred, gprob, opin, BS);
  prep_xh_k<<<(BS * 1024 / 8) / 256, 256, 0, stream>>>(x, Xh);
  gemm1_k<<<dim3(8, 256), 256, 0, stream>>>(Xh, W, bias, XT);
  scores_k<<<dim3(8, 8, 32), 256, 0, stream>>>(XT, Xh, opin, P, denom);
  pv_k<<<dim3(8, 8, 32), 256, 0, stream>>>(P, x, denom, out);
}

// Round 3
// 625.066 us; speedup vs baseline: 1.3691x; 1.1350x over previous
//
#include <hip/hip_runtime.h>

#define EPSF 1e-5f

typedef _Float16 f16x8 __attribute__((ext_vector_type(8)));
typedef float f32x4 __attribute__((ext_vector_type(4)));

__device__ __forceinline__ void gload_lds16(const _Float16* g, _Float16* l) {
  __builtin_amdgcn_global_load_lds(
      (const __attribute__((address_space(1))) unsigned int*)g,
      (__attribute__((address_space(3))) unsigned int*)l, 16, 0, 0);
}

__device__ __forceinline__ f16x8 cvt8(float4 a, float4 b) {
  f16x8 h;
  h[0] = (_Float16)a.x; h[1] = (_Float16)a.y; h[2] = (_Float16)a.z; h[3] = (_Float16)a.w;
  h[4] = (_Float16)b.x; h[5] = (_Float16)b.y; h[6] = (_Float16)b.z; h[7] = (_Float16)b.w;
  return h;
}

// ================= kernel 0a: opinion weights =================
__global__ void prep_opin_k(const float* __restrict__ gold, const float* __restrict__ pred,
                            const float* __restrict__ gprob, float* __restrict__ opin, int n) {
  int i = blockIdx.x * 256 + threadIdx.x;
  if (i >= n) return;
  float gp = gprob[0];
  float go = gold[i * 5 + 1] + gold[i * 5 + 2];
  float po = pred[i * 5 + 3] + pred[i * 5 + 4];
  opin[i] = gp * go + (1.0f - gp) * po;
}

// ================= kernel 0b: fp32 -> fp16 copy (x->Xh, W->Wh) =================
__global__ __launch_bounds__(256) void prep_h_k(const float* __restrict__ src,
                                                _Float16* __restrict__ dst) {
  long i = ((long)blockIdx.x * 256 + threadIdx.x) * 8;
  float4 a = *(const float4*)(src + i);
  float4 b = *(const float4*)(src + i + 4);
  *(f16x8*)(dst + i) = cvt8(a, b);
}

// ================= kernel 0c: XhT[b][d][t] = fp16(x[b][t][d]) =================
// grid (4 d-strips, 16 t-strips, 32 b), 256 thr. Reads 256B-coalesced, writes 32B chunks.
__global__ __launch_bounds__(256) void prep_xt_k(const float* __restrict__ x,
                                                 _Float16* __restrict__ XhT) {
  const int d = blockIdx.x * 256 + threadIdx.x;
  const int ts = blockIdx.y * 64;
  const long base = (long)blockIdx.z * 1024;
#pragma unroll
  for (int tg = 0; tg < 4; ++tg) {
    int t0 = ts + tg * 16;
    const float* src = x + (base + t0) * 1024 + d;
    float v[16];
#pragma unroll
    for (int j = 0; j < 16; ++j) v[j] = src[j * 1024];
    f16x8 h0, h1;
#pragma unroll
    for (int j = 0; j < 8; ++j) { h0[j] = (_Float16)v[j]; h1[j] = (_Float16)v[8 + j]; }
    _Float16* dst = XhT + (base + d) * 1024 + t0;
    *(f16x8*)dst = h0;
    *(f16x8*)(dst + 8) = h1;
  }
}

// ================= generic m97-style NT GEMM core (both operands fp16 K-contig) =====
// A: [M][K] at rowA*1024, B: [N][K] at rowB*1024, BK=32, tile 128x128, 4 waves.

// kernel 1 (big path): XT = fp16(Xh @ Wh^T + b)
__global__ __launch_bounds__(256) void gemm1_h_k(const _Float16* __restrict__ Xh,
                                                 const _Float16* __restrict__ Wh,
                                                 const float* __restrict__ bias,
                                                 _Float16* __restrict__ XT) {
  __shared__ _Float16 As[128 * 32];
  __shared__ _Float16 Bs[128 * 32];
  const int tid = threadIdx.x;
  const int wave = tid >> 6, lane = tid & 63;
  const int wm = wave >> 1, wn = wave & 1;
  const int quad = lane >> 4, nl = lane & 15;
  const long m0 = (long)blockIdx.y * 128;
  const int n0 = blockIdx.x * 128;

  f32x4 acc[4][4];
  f32x4 zero = {0.f, 0.f, 0.f, 0.f};
#pragma unroll
  for (int i = 0; i < 4; ++i)
#pragma unroll
    for (int j = 0; j < 4; ++j) acc[i][j] = zero;

  for (int k0 = 0; k0 < 1024; k0 += 32) {
#pragma unroll
    for (int it = 0; it < 2; ++it) {
      int c = it * 256 + tid;
      gload_lds16(Xh + (m0 + (c >> 2)) * 1024 + k0 + (c & 3) * 8,
                  &As[(it * 256 + wave * 64) * 8]);
      gload_lds16(Wh + (long)(n0 + (c >> 2)) * 1024 + k0 + (c & 3) * 8,
                  &Bs[(it * 256 + wave * 64) * 8]);
    }
    __syncthreads();
    f16x8 af[4], bf[4];
#pragma unroll
    for (int mi = 0; mi < 4; ++mi)
      af[mi] = *(const f16x8*)&As[(wm * 64 + mi * 16 + nl) * 32 + quad * 8];
#pragma unroll
    for (int ni = 0; ni < 4; ++ni)
      bf[ni] = *(const f16x8*)&Bs[(wn * 64 + ni * 16 + nl) * 32 + quad * 8];
#pragma unroll
    for (int mi = 0; mi < 4; ++mi)
#pragma unroll
      for (int ni = 0; ni < 4; ++ni)
        acc[mi][ni] = __builtin_amdgcn_mfma_f32_16x16x32_f16(af[mi], bf[ni], acc[mi][ni], 0, 0, 0);
    __syncthreads();
  }

#pragma unroll
  for (int mi = 0; mi < 4; ++mi) {
    long gm = m0 + wm * 64 + mi * 16 + quad * 4;
#pragma unroll
    for (int ni = 0; ni < 4; ++ni) {
      int gn = n0 + wn * 64 + ni * 16 + nl;
      float bv = bias[gn];
#pragma unroll
      for (int r = 0; r < 4; ++r)
        XT[(gm + r) * 1024 + gn] = (_Float16)(acc[mi][ni][r] + bv);
    }
  }
}

// kernel 1 (fallback): B from fp32 W
__global__ __launch_bounds__(256) void gemm1_k(const _Float16* __restrict__ Xh,
                                               const float* __restrict__ Wt,
                                               const float* __restrict__ bias,
                                               _Float16* __restrict__ XT) {
  __shared__ _Float16 As[128 * 32];
  __shared__ _Float16 Bs[128 * 32];
  const int tid = threadIdx.x;
  const int wave = tid >> 6, lane = tid & 63;
  const int wm = wave >> 1, wn = wave & 1;
  const int quad = lane >> 4, nl = lane & 15;
  const long m0 = (long)blockIdx.y * 128;
  const int n0 = blockIdx.x * 128;

  f32x4 acc[4][4];
  f32x4 zero = {0.f, 0.f, 0.f, 0.f};
#pragma unroll
  for (int i = 0; i < 4; ++i)
#pragma unroll
    for (int j = 0; j < 4; ++j) acc[i][j] = zero;

  const int crow = tid >> 2;
  const int ckc = (tid & 3) * 8;

  for (int k0 = 0; k0 < 1024; k0 += 32) {
#pragma unroll
    for (int it = 0; it < 2; ++it) {
      int c = it * 256 + tid;
      gload_lds16(Xh + (m0 + (c >> 2)) * 1024 + k0 + (c & 3) * 8,
                  &As[(it * 256 + wave * 64) * 8]);
      int row = it * 64 + crow;
      const float* sb = Wt + (long)(n0 + row) * 1024 + k0 + ckc;
      float4 b0 = *(const float4*)sb;
      float4 b1 = *(const float4*)(sb + 4);
      *(f16x8*)&Bs[row * 32 + ckc] = cvt8(b0, b1);
    }
    __syncthreads();
    f16x8 af[4], bf[4];
#pragma unroll
    for (int mi = 0; mi < 4; ++mi)
      af[mi] = *(const f16x8*)&As[(wm * 64 + mi * 16 + nl) * 32 + quad * 8];
#pragma unroll
    for (int ni = 0; ni < 4; ++ni)
      bf[ni] = *(const f16x8*)&Bs[(wn * 64 + ni * 16 + nl) * 32 + quad * 8];
#pragma unroll
    for (int mi = 0; mi < 4; ++mi)
#pragma unroll
      for (int ni = 0; ni < 4; ++ni)
        acc[mi][ni] = __builtin_amdgcn_mfma_f32_16x16x32_f16(af[mi], bf[ni], acc[mi][ni], 0, 0, 0);
    __syncthreads();
  }

#pragma unroll
  for (int mi = 0; mi < 4; ++mi) {
    long gm = m0 + wm * 64 + mi * 16 + quad * 4;
#pragma unroll
    for (int ni = 0; ni < 4; ++ni) {
      int gn = n0 + wn * 64 + ni * 16 + nl;
      float bv = bias[gn];
#pragma unroll
      for (int r = 0; r < 4; ++r)
        XT[(gm + r) * 1024 + gn] = (_Float16)(acc[mi][ni][r] + bv);
    }
  }
}

// ================= kernel 2: P = fp16(exp(tanh(XT @ Xh^T * decay * opin))), denom += rowsum ===
__global__ __launch_bounds__(256) void scores_k(const _Float16* __restrict__ XT,
                                                const _Float16* __restrict__ Xh,
                                                const float* __restrict__ opin,
                                                _Float16* __restrict__ P,
                                                float* __restrict__ denom) {
  __shared__ _Float16 As[128 * 32];
  __shared__ _Float16 Bs[128 * 32];
  const int tid = threadIdx.x;
  const int wave = tid >> 6, lane = tid & 63;
  const int wm = wave >> 1, wn = wave & 1;
  const int quad = lane >> 4, nl = lane & 15;
  const int b = blockIdx.z;
  const int s0 = blockIdx.y * 128;
  const int t0 = blockIdx.x * 128;
  const long base = (long)b * 1024;

  f32x4 acc[4][4];
  f32x4 zero = {0.f, 0.f, 0.f, 0.f};
#pragma unroll
  for (int i = 0; i < 4; ++i)
#pragma unroll
    for (int j = 0; j < 4; ++j) acc[i][j] = zero;

  for (int k0 = 0; k0 < 1024; k0 += 32) {
#pragma unroll
    for (int it = 0; it < 2; ++it) {
      int c = it * 256 + tid;
      gload_lds16(XT + (base + s0 + (c >> 2)) * 1024 + k0 + (c & 3) * 8,
                  &As[(it * 256 + wave * 64) * 8]);
      gload_lds16(Xh + (base + t0 + (c >> 2)) * 1024 + k0 + (c & 3) * 8,
                  &Bs[(it * 256 + wave * 64) * 8]);
    }
    __syncthreads();
    f16x8 af[4], bf[4];
#pragma unroll
    for (int mi = 0; mi < 4; ++mi)
      af[mi] = *(const f16x8*)&As[(wm * 64 + mi * 16 + nl) * 32 + quad * 8];
#pragma unroll
    for (int ni = 0; ni < 4; ++ni)
      bf[ni] = *(const f16x8*)&Bs[(wn * 64 + ni * 16 + nl) * 32 + quad * 8];
#pragma unroll
    for (int mi = 0; mi < 4; ++mi)
#pragma unroll
      for (int ni = 0; ni < 4; ++ni)
        acc[mi][ni] = __builtin_amdgcn_mfma_f32_16x16x32_f16(af[mi], bf[ni], acc[mi][ni], 0, 0, 0);
    __syncthreads();
  }

#pragma unroll
  for (int mi = 0; mi < 4; ++mi) {
#pragma unroll
    for (int r = 0; r < 4; ++r) {
      int s = s0 + wm * 64 + mi * 16 + quad * 4 + r;
      float opv = opin[b * 1024 + s];
      float rs = 0.f;
#pragma unroll
      for (int ni = 0; ni < 4; ++ni) {
        int t = t0 + wn * 64 + ni * 16 + nl;
        float loc = fabsf((float)(s - t));
        float arg = acc[mi][ni][r] * (1.0f / (loc + EPSF)) * opv;
        float th = 1.f - 2.f / (__expf(2.f * arg) + 1.f);  // tanh(arg)
        float p = __expf(th);
        if (s == t) p = 0.f;
        P[(base + s) * 1024 + t] = (_Float16)p;
        rs += p;
      }
      rs += __shfl_xor(rs, 1);
      rs += __shfl_xor(rs, 2);
      rs += __shfl_xor(rs, 4);
      rs += __shfl_xor(rs, 8);
      if (nl == 0) atomicAdd(&denom[b * 1024 + s], rs);
    }
  }
}

// ================= kernel 3 (big path): out = (P @ XhT^T) / (denom + eps) =====
// Pure m97 structure: both operands fp16 K-contiguous via global_load_lds.
__global__ __launch_bounds__(256) void pv_h_k(const _Float16* __restrict__ P,
                                              const _Float16* __restrict__ XhT,
                                              const float* __restrict__ denom,
                                              float* __restrict__ out) {
  __shared__ _Float16 As[128 * 32];
  __shared__ _Float16 Bs[128 * 32];
  const int tid = threadIdx.x;
  const int wave = tid >> 6, lane = tid & 63;
  const int wm = wave >> 1, wn = wave & 1;
  const int quad = lane >> 4, nl = lane & 15;
  const int b = blockIdx.z;
  const int s0 = blockIdx.y * 128;
  const int d0 = blockIdx.x * 128;
  const long base = (long)b * 1024;

  f32x4 acc[4][4];
  f32x4 zero = {0.f, 0.f, 0.f, 0.f};
#pragma unroll
  for (int i = 0; i < 4; ++i)
#pragma unroll
    for (int j = 0; j < 4; ++j) acc[i][j] = zero;

  for (int k0 = 0; k0 < 1024; k0 += 32) {
#pragma unroll
    for (int it = 0; it < 2; ++it) {
      int c = it * 256 + tid;
      gload_lds16(P + (base + s0 + (c >> 2)) * 1024 + k0 + (c & 3) * 8,
                  &As[(it * 256 + wave * 64) * 8]);
      gload_lds16(XhT + (base + d0 + (c >> 2)) * 1024 + k0 + (c & 3) * 8,
                  &Bs[(it * 256 + wave * 64) * 8]);
    }
    __syncthreads();
    f16x8 af[4], bf[4];
#pragma unroll
    for (int mi = 0; mi < 4; ++mi)
      af[mi] = *(const f16x8*)&As[(wm * 64 + mi * 16 + nl) * 32 + quad * 8];
#pragma unroll
    for (int ni = 0; ni < 4; ++ni)
      bf[ni] = *(const f16x8*)&Bs[(wn * 64 + ni * 16 + nl) * 32 + quad * 8];
#pragma unroll
    for (int mi = 0; mi < 4; ++mi)
#pragma unroll
      for (int ni = 0; ni < 4; ++ni)
        acc[mi][ni] = __builtin_amdgcn_mfma_f32_16x16x32_f16(af[mi], bf[ni], acc[mi][ni], 0, 0, 0);
    __syncthreads();
  }

#pragma unroll
  for (int mi = 0; mi < 4; ++mi) {
#pragma unroll
    for (int r = 0; r < 4; ++r) {
      int s = s0 + wm * 64 + mi * 16 + quad * 4 + r;
      float inv = 1.0f / (denom[b * 1024 + s] + EPSF);
#pragma unroll
      for (int ni = 0; ni < 4; ++ni) {
        int d = d0 + wn * 64 + ni * 16 + nl;
        out[(base + s) * 1024 + d] = acc[mi][ni][r] * inv;
      }
    }
  }
}

// ================= kernel 3 (fallback): in-kernel gather transpose =============
__global__ __launch_bounds__(256) void pv_k(const _Float16* __restrict__ P,
                                            const float* __restrict__ X,
                                            const float* __restrict__ denom,
                                            float* __restrict__ out) {
  __shared__ _Float16 As[128 * 32];
  __shared__ _Float16 BsT[128 * 40];
  const int tid = threadIdx.x;
  const int wave = tid >> 6, lane = tid & 63;
  const int wm = wave >> 1, wn = wave & 1;
  const int quad = lane >> 4, nl = lane & 15;
  const int b = blockIdx.z;
  const int s0 = blockIdx.y * 128;
  const int d0 = blockIdx.x * 128;
  const long base = (long)b * 1024;

  const int dcol = tid & 127;
  const int tg = tid >> 7;

  f32x4 acc[4][4];
  f32x4 zero = {0.f, 0.f, 0.f, 0.f};
#pragma unroll
  for (int i = 0; i < 4; ++i)
#pragma unroll
    for (int j = 0; j < 4; ++j) acc[i][j] = zero;

  for (int k0 = 0; k0 < 1024; k0 += 32) {
#pragma unroll
    for (int it = 0; it < 2; ++it) {
      int c = it * 256 + tid;
      gload_lds16(P + (base + s0 + (c >> 2)) * 1024 + k0 + (c & 3) * 8,
                  &As[(it * 256 + wave * 64) * 8]);
    }
    {
      const float* xb = X + (base + k0 + tg * 16) * 1024 + d0 + dcol;
      float v[16];
#pragma unroll
      for (int j = 0; j < 16; ++j) v[j] = xb[j * 1024];
      f16x8 h0, h1;
#pragma unroll
      for (int j = 0; j < 8; ++j) { h0[j] = (_Float16)v[j]; h1[j] = (_Float16)v[8 + j]; }
      *(f16x8*)&BsT[dcol * 40 + tg * 16] = h0;
      *(f16x8*)&BsT[dcol * 40 + tg * 16 + 8] = h1;
    }
    __syncthreads();
    f16x8 af[4], bf[4];
#pragma unroll
    for (int mi = 0; mi < 4; ++mi)
      af[mi] = *(const f16x8*)&As[(wm * 64 + mi * 16 + nl) * 32 + quad * 8];
#pragma unroll
    for (int ni = 0; ni < 4; ++ni)
      bf[ni] = *(const f16x8*)&BsT[(wn * 64 + ni * 16 + nl) * 40 + quad * 8];
#pragma unroll
    for (int mi = 0; mi < 4; ++mi)
#pragma unroll
      for (int ni = 0; ni < 4; ++ni)
        acc[mi][ni] = __builtin_amdgcn_mfma_f32_16x16x32_f16(af[mi], bf[ni], acc[mi][ni], 0, 0, 0);
    __syncthreads();
  }

#pragma unroll
  for (int mi = 0; mi < 4; ++mi) {
#pragma unroll
    for (int r = 0; r < 4; ++r) {
      int s = s0 + wm * 64 + mi * 16 + quad * 4 + r;
      float inv = 1.0f / (denom[b * 1024 + s] + EPSF);
#pragma unroll
      for (int ni = 0; ni < 4; ++ni) {
        int d = d0 + wn * 64 + ni * 16 + nl;
        out[(base + s) * 1024 + d] = acc[mi][ni][r] * inv;
      }
    }
  }
}

extern "C" void kernel_launch(void* const* d_in, const int* in_sizes, int n_in,
                              void* d_out, int out_size, void* d_ws, size_t ws_size,
                              hipStream_t stream) {
  (void)in_sizes; (void)n_in; (void)out_size;
  const int B = 32, S = 1024;
  const int BS = B * S;

  const float* x     = (const float*)d_in[0];
  const float* W     = (const float*)d_in[1];
  const float* bias  = (const float*)d_in[2];
  const float* gold  = (const float*)d_in[3];
  const float* pred  = (const float*)d_in[4];
  const float* gprob = (const float*)d_in[5];

  const size_t P_BYTES  = (size_t)BS * 1024 * sizeof(_Float16);   // 64 MB
  const size_t XT_BYTES = P_BYTES;                                // 64 MB
  const size_t OPIN_B   = (size_t)BS * sizeof(float);             // 128 KB
  const size_t WH_B     = (size_t)1024 * 1024 * sizeof(_Float16); // 2 MB
  const size_t NEED_BIG = P_BYTES + XT_BYTES + 2 * OPIN_B + WH_B;

  char* ws = (char*)d_ws;
  _Float16* P = (_Float16*)ws;
  const bool big = ws_size >= NEED_BIG;

  // d_out double-duty: front 64MB = XT (fp16), back 64MB = Xh (fp16);
  // both dead before the PV kernel overwrites d_out with fp32 output.
  _Float16* XT = (_Float16*)d_out;
  _Float16* Xh = XT + (size_t)BS * 1024;
  float* out   = (float*)d_out;

  if (big) {
    _Float16* XhT = (_Float16*)(ws + P_BYTES);
    float* opin   = (float*)(ws + P_BYTES + XT_BYTES);
    float* denom  = opin + BS;
    _Float16* Wh  = (_Float16*)(ws + P_BYTES + XT_BYTES + 2 * OPIN_B);

    hipMemsetAsync(denom, 0, OPIN_B, stream);
    prep_opin_k<<<BS / 256, 256, 0, stream>>>(gold, pred, gprob, opin, BS);
    prep_h_k<<<(BS * 1024 / 8) / 256, 256, 0, stream>>>(x, Xh);
    prep_h_k<<<(1024 * 1024 / 8) / 256, 256, 0, stream>>>(W, Wh);
    prep_xt_k<<<dim3(4, 16, 32), 256, 0, stream>>>(x, XhT);
    gemm1_h_k<<<dim3(8, 256), 256, 0, stream>>>(Xh, Wh, bias, XT);
    scores_k<<<dim3(8, 8, 32), 256, 0, stream>>>(XT, Xh, opin, P, denom);
    pv_h_k<<<dim3(8, 8, 32), 256, 0, stream>>>(P, XhT, denom, out);
  } else {
    float* opin  = (float*)(ws + P_BYTES);
    float* denom = opin + BS;

    hipMemsetAsync(denom, 0, OPIN_B, stream);
    prep_opin_k<<<BS / 256, 256, 0, stream>>>(gold, pred, gprob, opin, BS);
    prep_h_k<<<(BS * 1024 / 8) / 256, 256, 0, stream>>>(x, Xh);
    gemm1_k<<<dim3(8, 256), 256, 0, stream>>>(Xh, W, bias, XT);
    scores_k<<<dim3(8, 8, 32), 256, 0, stream>>>(XT, Xh, opin, P, denom);
    pv_k<<<dim3(8, 8, 32), 256, 0, stream>>>(P, x, denom, out);
  }
}

// Round 4
// 597.232 us; speedup vs baseline: 1.4329x; 1.0466x over previous
//
#include <hip/hip_runtime.h>

#define EPSF 1e-5f

typedef _Float16 f16x8 __attribute__((ext_vector_type(8)));
typedef float f32x4 __attribute__((ext_vector_type(4)));

__device__ __forceinline__ void gload_lds16(const _Float16* g, _Float16* l) {
  __builtin_amdgcn_global_load_lds(
      (const __attribute__((address_space(1))) unsigned int*)g,
      (__attribute__((address_space(3))) unsigned int*)l, 16, 0, 0);
}

__device__ __forceinline__ f16x8 cvt8(float4 a, float4 b) {
  f16x8 h;
  h[0] = (_Float16)a.x; h[1] = (_Float16)a.y; h[2] = (_Float16)a.z; h[3] = (_Float16)a.w;
  h[4] = (_Float16)b.x; h[5] = (_Float16)b.y; h[6] = (_Float16)b.z; h[7] = (_Float16)b.w;
  return h;
}

// ================= kernel 0a: opinion weights =================
__global__ void prep_opin_k(const float* __restrict__ gold, const float* __restrict__ pred,
                            const float* __restrict__ gprob, float* __restrict__ opin, int n) {
  int i = blockIdx.x * 256 + threadIdx.x;
  if (i >= n) return;
  float gp = gprob[0];
  float go = gold[i * 5 + 1] + gold[i * 5 + 2];
  float po = pred[i * 5 + 3] + pred[i * 5 + 4];
  opin[i] = gp * go + (1.0f - gp) * po;
}

// ================= kernel 0b: fp32 -> fp16 copy (x->Xh, W->Wh) =================
__global__ __launch_bounds__(256) void prep_h_k(const float* __restrict__ src,
                                                _Float16* __restrict__ dst) {
  long i = ((long)blockIdx.x * 256 + threadIdx.x) * 8;
  float4 a = *(const float4*)(src + i);
  float4 b = *(const float4*)(src + i + 4);
  *(f16x8*)(dst + i) = cvt8(a, b);
}

// ================= kernel 0c: XhT[b][d][t] = fp16(x[b][t][d]) =================
__global__ __launch_bounds__(256) void prep_xt_k(const float* __restrict__ x,
                                                 _Float16* __restrict__ XhT) {
  const int d = blockIdx.x * 256 + threadIdx.x;
  const int ts = blockIdx.y * 64;
  const long base = (long)blockIdx.z * 1024;
#pragma unroll
  for (int tg = 0; tg < 4; ++tg) {
    int t0 = ts + tg * 16;
    const float* src = x + (base + t0) * 1024 + d;
    float v[16];
#pragma unroll
    for (int j = 0; j < 16; ++j) v[j] = src[j * 1024];
    f16x8 h0, h1;
#pragma unroll
    for (int j = 0; j < 8; ++j) { h0[j] = (_Float16)v[j]; h1[j] = (_Float16)v[8 + j]; }
    _Float16* dst = XhT + (base + d) * 1024 + t0;
    *(f16x8*)dst = h0;
    *(f16x8*)(dst + 8) = h1;
  }
}

// ================= kernel 1 (big path): XT = fp16(Xh @ Wh^T + b) =================
__global__ __launch_bounds__(256) void gemm1_h_k(const _Float16* __restrict__ Xh,
                                                 const _Float16* __restrict__ Wh,
                                                 const float* __restrict__ bias,
                                                 _Float16* __restrict__ XT) {
  __shared__ _Float16 As[128 * 32];
  __shared__ _Float16 Bs[128 * 32];
  const int tid = threadIdx.x;
  const int wave = tid >> 6, lane = tid & 63;
  const int wm = wave >> 1, wn = wave & 1;
  const int quad = lane >> 4, nl = lane & 15;
  const long m0 = (long)blockIdx.y * 128;
  const int n0 = blockIdx.x * 128;

  f32x4 acc[4][4];
  f32x4 zero = {0.f, 0.f, 0.f, 0.f};
#pragma unroll
  for (int i = 0; i < 4; ++i)
#pragma unroll
    for (int j = 0; j < 4; ++j) acc[i][j] = zero;

  for (int k0 = 0; k0 < 1024; k0 += 32) {
#pragma unroll
    for (int it = 0; it < 2; ++it) {
      int c = it * 256 + tid;
      gload_lds16(Xh + (m0 + (c >> 2)) * 1024 + k0 + (c & 3) * 8,
                  &As[(it * 256 + wave * 64) * 8]);
      gload_lds16(Wh + (long)(n0 + (c >> 2)) * 1024 + k0 + (c & 3) * 8,
                  &Bs[(it * 256 + wave * 64) * 8]);
    }
    __syncthreads();
    f16x8 af[4], bf[4];
#pragma unroll
    for (int mi = 0; mi < 4; ++mi)
      af[mi] = *(const f16x8*)&As[(wm * 64 + mi * 16 + nl) * 32 + quad * 8];
#pragma unroll
    for (int ni = 0; ni < 4; ++ni)
      bf[ni] = *(const f16x8*)&Bs[(wn * 64 + ni * 16 + nl) * 32 + quad * 8];
#pragma unroll
    for (int mi = 0; mi < 4; ++mi)
#pragma unroll
      for (int ni = 0; ni < 4; ++ni)
        acc[mi][ni] = __builtin_amdgcn_mfma_f32_16x16x32_f16(af[mi], bf[ni], acc[mi][ni], 0, 0, 0);
    __syncthreads();
  }

#pragma unroll
  for (int mi = 0; mi < 4; ++mi) {
    long gm = m0 + wm * 64 + mi * 16 + quad * 4;
#pragma unroll
    for (int ni = 0; ni < 4; ++ni) {
      int gn = n0 + wn * 64 + ni * 16 + nl;
      float bv = bias[gn];
#pragma unroll
      for (int r = 0; r < 4; ++r)
        XT[(gm + r) * 1024 + gn] = (_Float16)(acc[mi][ni][r] + bv);
    }
  }
}

// kernel 1 (fallback): B from fp32 W
__global__ __launch_bounds__(256) void gemm1_k(const _Float16* __restrict__ Xh,
                                               const float* __restrict__ Wt,
                                               const float* __restrict__ bias,
                                               _Float16* __restrict__ XT) {
  __shared__ _Float16 As[128 * 32];
  __shared__ _Float16 Bs[128 * 32];
  const int tid = threadIdx.x;
  const int wave = tid >> 6, lane = tid & 63;
  const int wm = wave >> 1, wn = wave & 1;
  const int quad = lane >> 4, nl = lane & 15;
  const long m0 = (long)blockIdx.y * 128;
  const int n0 = blockIdx.x * 128;

  f32x4 acc[4][4];
  f32x4 zero = {0.f, 0.f, 0.f, 0.f};
#pragma unroll
  for (int i = 0; i < 4; ++i)
#pragma unroll
    for (int j = 0; j < 4; ++j) acc[i][j] = zero;

  const int crow = tid >> 2;
  const int ckc = (tid & 3) * 8;

  for (int k0 = 0; k0 < 1024; k0 += 32) {
#pragma unroll
    for (int it = 0; it < 2; ++it) {
      int c = it * 256 + tid;
      gload_lds16(Xh + (m0 + (c >> 2)) * 1024 + k0 + (c & 3) * 8,
                  &As[(it * 256 + wave * 64) * 8]);
      int row = it * 64 + crow;
      const float* sb = Wt + (long)(n0 + row) * 1024 + k0 + ckc;
      float4 b0 = *(const float4*)sb;
      float4 b1 = *(const float4*)(sb + 4);
      *(f16x8*)&Bs[row * 32 + ckc] = cvt8(b0, b1);
    }
    __syncthreads();
    f16x8 af[4], bf[4];
#pragma unroll
    for (int mi = 0; mi < 4; ++mi)
      af[mi] = *(const f16x8*)&As[(wm * 64 + mi * 16 + nl) * 32 + quad * 8];
#pragma unroll
    for (int ni = 0; ni < 4; ++ni)
      bf[ni] = *(const f16x8*)&Bs[(wn * 64 + ni * 16 + nl) * 32 + quad * 8];
#pragma unroll
    for (int mi = 0; mi < 4; ++mi)
#pragma unroll
      for (int ni = 0; ni < 4; ++ni)
        acc[mi][ni] = __builtin_amdgcn_mfma_f32_16x16x32_f16(af[mi], bf[ni], acc[mi][ni], 0, 0, 0);
    __syncthreads();
  }

#pragma unroll
  for (int mi = 0; mi < 4; ++mi) {
    long gm = m0 + wm * 64 + mi * 16 + quad * 4;
#pragma unroll
    for (int ni = 0; ni < 4; ++ni) {
      int gn = n0 + wn * 64 + ni * 16 + nl;
      float bv = bias[gn];
#pragma unroll
      for (int r = 0; r < 4; ++r)
        XT[(gm + r) * 1024 + gn] = (_Float16)(acc[mi][ni][r] + bv);
    }
  }
}

// ================= kernel 2: P = fp16(exp(tanh(XT @ Xh^T * decay * opin))), denom += rowsum ===
// 1D grid 2048, XCD/batch-affine swizzle: lin&7 = presumed XCD class -> 4 batches each,
// 64 consecutive blocks of a class share one batch's 4MB working set (fits per-XCD L2).
__global__ __launch_bounds__(256) void scores_k(const _Float16* __restrict__ XT,
                                                const _Float16* __restrict__ Xh,
                                                const float* __restrict__ opin,
                                                _Float16* __restrict__ P,
                                                float* __restrict__ denom) {
  __shared__ _Float16 As[128 * 32];
  __shared__ _Float16 Bs[128 * 32];
  const int tid = threadIdx.x;
  const int wave = tid >> 6, lane = tid & 63;
  const int wm = wave >> 1, wn = wave & 1;
  const int quad = lane >> 4, nl = lane & 15;

  const int lin = blockIdx.x;
  const int xcd = lin & 7;
  const int i = lin >> 3;              // 0..255
  const int b = xcd + 8 * (i >> 6);    // 4 batches per class
  const int tile = i & 63;
  const int s0 = (tile >> 3) * 128;
  const int t0 = (tile & 7) * 128;
  const long base = (long)b * 1024;

  f32x4 acc[4][4];
  f32x4 zero = {0.f, 0.f, 0.f, 0.f};
#pragma unroll
  for (int i2 = 0; i2 < 4; ++i2)
#pragma unroll
    for (int j = 0; j < 4; ++j) acc[i2][j] = zero;

  for (int k0 = 0; k0 < 1024; k0 += 32) {
#pragma unroll
    for (int it = 0; it < 2; ++it) {
      int c = it * 256 + tid;
      gload_lds16(XT + (base + s0 + (c >> 2)) * 1024 + k0 + (c & 3) * 8,
                  &As[(it * 256 + wave * 64) * 8]);
      gload_lds16(Xh + (base + t0 + (c >> 2)) * 1024 + k0 + (c & 3) * 8,
                  &Bs[(it * 256 + wave * 64) * 8]);
    }
    __syncthreads();
    f16x8 af[4], bf[4];
#pragma unroll
    for (int mi = 0; mi < 4; ++mi)
      af[mi] = *(const f16x8*)&As[(wm * 64 + mi * 16 + nl) * 32 + quad * 8];
#pragma unroll
    for (int ni = 0; ni < 4; ++ni)
      bf[ni] = *(const f16x8*)&Bs[(wn * 64 + ni * 16 + nl) * 32 + quad * 8];
#pragma unroll
    for (int mi = 0; mi < 4; ++mi)
#pragma unroll
      for (int ni = 0; ni < 4; ++ni)
        acc[mi][ni] = __builtin_amdgcn_mfma_f32_16x16x32_f16(af[mi], bf[ni], acc[mi][ni], 0, 0, 0);
    __syncthreads();
  }

#pragma unroll
  for (int mi = 0; mi < 4; ++mi) {
#pragma unroll
    for (int r = 0; r < 4; ++r) {
      int s = s0 + wm * 64 + mi * 16 + quad * 4 + r;
      float opv = opin[b * 1024 + s];
      float rs = 0.f;
#pragma unroll
      for (int ni = 0; ni < 4; ++ni) {
        int t = t0 + wn * 64 + ni * 16 + nl;
        float loc = fabsf((float)(s - t));
        float arg = acc[mi][ni][r] * (1.0f / (loc + EPSF)) * opv;
        float th = 1.f - 2.f / (__expf(2.f * arg) + 1.f);  // tanh(arg)
        float p = __expf(th);
        if (s == t) p = 0.f;
        P[(base + s) * 1024 + t] = (_Float16)p;
        rs += p;
      }
      rs += __shfl_xor(rs, 1);
      rs += __shfl_xor(rs, 2);
      rs += __shfl_xor(rs, 4);
      rs += __shfl_xor(rs, 8);
      if (nl == 0) atomicAdd(&denom[b * 1024 + s], rs);
    }
  }
}

// ================= kernel 3 (big path): out = (P @ XhT^T) / (denom + eps), swizzled =====
__global__ __launch_bounds__(256) void pv_h_k(const _Float16* __restrict__ P,
                                              const _Float16* __restrict__ XhT,
                                              const float* __restrict__ denom,
                                              float* __restrict__ out) {
  __shared__ _Float16 As[128 * 32];
  __shared__ _Float16 Bs[128 * 32];
  const int tid = threadIdx.x;
  const int wave = tid >> 6, lane = tid & 63;
  const int wm = wave >> 1, wn = wave & 1;
  const int quad = lane >> 4, nl = lane & 15;

  const int lin = blockIdx.x;
  const int xcd = lin & 7;
  const int i = lin >> 3;
  const int b = xcd + 8 * (i >> 6);
  const int tile = i & 63;
  const int s0 = (tile >> 3) * 128;
  const int d0 = (tile & 7) * 128;
  const long base = (long)b * 1024;

  f32x4 acc[4][4];
  f32x4 zero = {0.f, 0.f, 0.f, 0.f};
#pragma unroll
  for (int i2 = 0; i2 < 4; ++i2)
#pragma unroll
    for (int j = 0; j < 4; ++j) acc[i2][j] = zero;

  for (int k0 = 0; k0 < 1024; k0 += 32) {
#pragma unroll
    for (int it = 0; it < 2; ++it) {
      int c = it * 256 + tid;
      gload_lds16(P + (base + s0 + (c >> 2)) * 1024 + k0 + (c & 3) * 8,
                  &As[(it * 256 + wave * 64) * 8]);
      gload_lds16(XhT + (base + d0 + (c >> 2)) * 1024 + k0 + (c & 3) * 8,
                  &Bs[(it * 256 + wave * 64) * 8]);
    }
    __syncthreads();
    f16x8 af[4], bf[4];
#pragma unroll
    for (int mi = 0; mi < 4; ++mi)
      af[mi] = *(const f16x8*)&As[(wm * 64 + mi * 16 + nl) * 32 + quad * 8];
#pragma unroll
    for (int ni = 0; ni < 4; ++ni)
      bf[ni] = *(const f16x8*)&Bs[(wn * 64 + ni * 16 + nl) * 32 + quad * 8];
#pragma unroll
    for (int mi = 0; mi < 4; ++mi)
#pragma unroll
      for (int ni = 0; ni < 4; ++ni)
        acc[mi][ni] = __builtin_amdgcn_mfma_f32_16x16x32_f16(af[mi], bf[ni], acc[mi][ni], 0, 0, 0);
    __syncthreads();
  }

#pragma unroll
  for (int mi = 0; mi < 4; ++mi) {
#pragma unroll
    for (int r = 0; r < 4; ++r) {
      int s = s0 + wm * 64 + mi * 16 + quad * 4 + r;
      float inv = 1.0f / (denom[b * 1024 + s] + EPSF);
#pragma unroll
      for (int ni = 0; ni < 4; ++ni) {
        int d = d0 + wn * 64 + ni * 16 + nl;
        out[(base + s) * 1024 + d] = acc[mi][ni][r] * inv;
      }
    }
  }
}

// ================= kernel 3 (fallback): in-kernel gather transpose =============
__global__ __launch_bounds__(256) void pv_k(const _Float16* __restrict__ P,
                                            const float* __restrict__ X,
                                            const float* __restrict__ denom,
                                            float* __restrict__ out) {
  __shared__ _Float16 As[128 * 32];
  __shared__ _Float16 BsT[128 * 40];
  const int tid = threadIdx.x;
  const int wave = tid >> 6, lane = tid & 63;
  const int wm = wave >> 1, wn = wave & 1;
  const int quad = lane >> 4, nl = lane & 15;
  const int b = blockIdx.z;
  const int s0 = blockIdx.y * 128;
  const int d0 = blockIdx.x * 128;
  const long base = (long)b * 1024;

  const int dcol = tid & 127;
  const int tg = tid >> 7;

  f32x4 acc[4][4];
  f32x4 zero = {0.f, 0.f, 0.f, 0.f};
#pragma unroll
  for (int i = 0; i < 4; ++i)
#pragma unroll
    for (int j = 0; j < 4; ++j) acc[i][j] = zero;

  for (int k0 = 0; k0 < 1024; k0 += 32) {
#pragma unroll
    for (int it = 0; it < 2; ++it) {
      int c = it * 256 + tid;
      gload_lds16(P + (base + s0 + (c >> 2)) * 1024 + k0 + (c & 3) * 8,
                  &As[(it * 256 + wave * 64) * 8]);
    }
    {
      const float* xb = X + (base + k0 + tg * 16) * 1024 + d0 + dcol;
      float v[16];
#pragma unroll
      for (int j = 0; j < 16; ++j) v[j] = xb[j * 1024];
      f16x8 h0, h1;
#pragma unroll
      for (int j = 0; j < 8; ++j) { h0[j] = (_Float16)v[j]; h1[j] = (_Float16)v[8 + j]; }
      *(f16x8*)&BsT[dcol * 40 + tg * 16] = h0;
      *(f16x8*)&BsT[dcol * 40 + tg * 16 + 8] = h1;
    }
    __syncthreads();
    f16x8 af[4], bf[4];
#pragma unroll
    for (int mi = 0; mi < 4; ++mi)
      af[mi] = *(const f16x8*)&As[(wm * 64 + mi * 16 + nl) * 32 + quad * 8];
#pragma unroll
    for (int ni = 0; ni < 4; ++ni)
      bf[ni] = *(const f16x8*)&BsT[(wn * 64 + ni * 16 + nl) * 40 + quad * 8];
#pragma unroll
    for (int mi = 0; mi < 4; ++mi)
#pragma unroll
      for (int ni = 0; ni < 4; ++ni)
        acc[mi][ni] = __builtin_amdgcn_mfma_f32_16x16x32_f16(af[mi], bf[ni], acc[mi][ni], 0, 0, 0);
    __syncthreads();
  }

#pragma unroll
  for (int mi = 0; mi < 4; ++mi) {
#pragma unroll
    for (int r = 0; r < 4; ++r) {
      int s = s0 + wm * 64 + mi * 16 + quad * 4 + r;
      float inv = 1.0f / (denom[b * 1024 + s] + EPSF);
#pragma unroll
      for (int ni = 0; ni < 4; ++ni) {
        int d = d0 + wn * 64 + ni * 16 + nl;
        out[(base + s) * 1024 + d] = acc[mi][ni][r] * inv;
      }
    }
  }
}

// fallback scores (3D grid, no swizzle) — used only when ws is small
__global__ __launch_bounds__(256) void scores_f_k(const _Float16* __restrict__ XT,
                                                  const _Float16* __restrict__ Xh,
                                                  const float* __restrict__ opin,
                                                  _Float16* __restrict__ P,
                                                  float* __restrict__ denom) {
  __shared__ _Float16 As[128 * 32];
  __shared__ _Float16 Bs[128 * 32];
  const int tid = threadIdx.x;
  const int wave = tid >> 6, lane = tid & 63;
  const int wm = wave >> 1, wn = wave & 1;
  const int quad = lane >> 4, nl = lane & 15;
  const int b = blockIdx.z;
  const int s0 = blockIdx.y * 128;
  const int t0 = blockIdx.x * 128;
  const long base = (long)b * 1024;

  f32x4 acc[4][4];
  f32x4 zero = {0.f, 0.f, 0.f, 0.f};
#pragma unroll
  for (int i = 0; i < 4; ++i)
#pragma unroll
    for (int j = 0; j < 4; ++j) acc[i][j] = zero;

  for (int k0 = 0; k0 < 1024; k0 += 32) {
#pragma unroll
    for (int it = 0; it < 2; ++it) {
      int c = it * 256 + tid;
      gload_lds16(XT + (base + s0 + (c >> 2)) * 1024 + k0 + (c & 3) * 8,
                  &As[(it * 256 + wave * 64) * 8]);
      gload_lds16(Xh + (base + t0 + (c >> 2)) * 1024 + k0 + (c & 3) * 8,
                  &Bs[(it * 256 + wave * 64) * 8]);
    }
    __syncthreads();
    f16x8 af[4], bf[4];
#pragma unroll
    for (int mi = 0; mi < 4; ++mi)
      af[mi] = *(const f16x8*)&As[(wm * 64 + mi * 16 + nl) * 32 + quad * 8];
#pragma unroll
    for (int ni = 0; ni < 4; ++ni)
      bf[ni] = *(const f16x8*)&Bs[(wn * 64 + ni * 16 + nl) * 32 + quad * 8];
#pragma unroll
    for (int mi = 0; mi < 4; ++mi)
#pragma unroll
      for (int ni = 0; ni < 4; ++ni)
        acc[mi][ni] = __builtin_amdgcn_mfma_f32_16x16x32_f16(af[mi], bf[ni], acc[mi][ni], 0, 0, 0);
    __syncthreads();
  }

#pragma unroll
  for (int mi = 0; mi < 4; ++mi) {
#pragma unroll
    for (int r = 0; r < 4; ++r) {
      int s = s0 + wm * 64 + mi * 16 + quad * 4 + r;
      float opv = opin[b * 1024 + s];
      float rs = 0.f;
#pragma unroll
      for (int ni = 0; ni < 4; ++ni) {
        int t = t0 + wn * 64 + ni * 16 + nl;
        float loc = fabsf((float)(s - t));
        float arg = acc[mi][ni][r] * (1.0f / (loc + EPSF)) * opv;
        float th = 1.f - 2.f / (__expf(2.f * arg) + 1.f);
        float p = __expf(th);
        if (s == t) p = 0.f;
        P[(base + s) * 1024 + t] = (_Float16)p;
        rs += p;
      }
      rs += __shfl_xor(rs, 1);
      rs += __shfl_xor(rs, 2);
      rs += __shfl_xor(rs, 4);
      rs += __shfl_xor(rs, 8);
      if (nl == 0) atomicAdd(&denom[b * 1024 + s], rs);
    }
  }
}

extern "C" void kernel_launch(void* const* d_in, const int* in_sizes, int n_in,
                              void* d_out, int out_size, void* d_ws, size_t ws_size,
                              hipStream_t stream) {
  (void)in_sizes; (void)n_in; (void)out_size;
  const int B = 32, S = 1024;
  const int BS = B * S;

  const float* x     = (const float*)d_in[0];
  const float* W     = (const float*)d_in[1];
  const float* bias  = (const float*)d_in[2];
  const float* gold  = (const float*)d_in[3];
  const float* pred  = (const float*)d_in[4];
  const float* gprob = (const float*)d_in[5];

  const size_t P_BYTES  = (size_t)BS * 1024 * sizeof(_Float16);   // 64 MB
  const size_t XT_BYTES = P_BYTES;                                // 64 MB
  const size_t OPIN_B   = (size_t)BS * sizeof(float);             // 128 KB
  const size_t WH_B     = (size_t)1024 * 1024 * sizeof(_Float16); // 2 MB
  const size_t NEED_BIG = P_BYTES + XT_BYTES + 2 * OPIN_B + WH_B;

  char* ws = (char*)d_ws;
  _Float16* P = (_Float16*)ws;
  const bool big = ws_size >= NEED_BIG;

  // d_out double-duty: front 64MB = XT (fp16), back 64MB = Xh (fp16);
  // both dead before the PV kernel overwrites d_out with fp32 output.
  _Float16* XT = (_Float16*)d_out;
  _Float16* Xh = XT + (size_t)BS * 1024;
  float* out   = (float*)d_out;

  if (big) {
    _Float16* XhT = (_Float16*)(ws + P_BYTES);
    float* opin   = (float*)(ws + P_BYTES + XT_BYTES);
    float* denom  = opin + BS;
    _Float16* Wh  = (_Float16*)(ws + P_BYTES + XT_BYTES + 2 * OPIN_B);

    hipMemsetAsync(denom, 0, OPIN_B, stream);
    prep_opin_k<<<BS / 256, 256, 0, stream>>>(gold, pred, gprob, opin, BS);
    prep_h_k<<<(BS * 1024 / 8) / 256, 256, 0, stream>>>(x, Xh);
    prep_h_k<<<(1024 * 1024 / 8) / 256, 256, 0, stream>>>(W, Wh);
    prep_xt_k<<<dim3(4, 16, 32), 256, 0, stream>>>(x, XhT);
    gemm1_h_k<<<dim3(8, 256), 256, 0, stream>>>(Xh, Wh, bias, XT);
    scores_k<<<2048, 256, 0, stream>>>(XT, Xh, opin, P, denom);
    pv_h_k<<<2048, 256, 0, stream>>>(P, XhT, denom, out);
  } else {
    float* opin  = (float*)(ws + P_BYTES);
    float* denom = opin + BS;

    hipMemsetAsync(denom, 0, OPIN_B, stream);
    prep_opin_k<<<BS / 256, 256, 0, stream>>>(gold, pred, gprob, opin, BS);
    prep_h_k<<<(BS * 1024 / 8) / 256, 256, 0, stream>>>(x, Xh);
    gemm1_k<<<dim3(8, 256), 256, 0, stream>>>(Xh, W, bias, XT);
    scores_f_k<<<dim3(8, 8, 32), 256, 0, stream>>>(XT, Xh, opin, P, denom);
    pv_k<<<dim3(8, 8, 32), 256, 0, stream>>>(P, x, denom, out);
  }
}